// Round 17
// baseline (1982.540 us; speedup 1.0000x reference)
//
#include <hip/hip_runtime.h>
#include <math.h>

typedef unsigned short ushort_t;
typedef short bf16x8 __attribute__((ext_vector_type(8)));   // 8 bf16 = 4 VGPRs (MFMA A/B frag)
typedef float f32x4 __attribute__((ext_vector_type(4)));    // MFMA C/D frag

#define BN_ 4096
#define SN 24
#define TN 24
#define EN 128
#define HN 512
#define GN 1536
#define VN 256
#define BOW_ 1
#define HC 1024   // hcat row stride: [hi(512) | lo(512)]
// Recurrent GEMMs: 2-term split, 16 chunks of BK=32, B STAGED ONCE per chunk:
//   per kc: stage {A-hi(k=kc*32), A-lo(k=512+kc*32), B chunk kc}; acc += Ahi x B + Alo x B.
// Logits: 3-term split, 48 chunks of BK=32 (Ahi x Wohi, Alo x Wohi, Ahi x Wolo).

__device__ __forceinline__ float bf2f(ushort_t u) {
    union { unsigned int i; float f; } v; v.i = ((unsigned int)u) << 16; return v.f;
}
__device__ __forceinline__ ushort_t f2bf(float f) {  // round-to-nearest-even
    union { float f; unsigned int i; } v; v.f = f;
    unsigned int r = (v.i + 0x7FFFu + ((v.i >> 16) & 1u)) >> 16;
    return (ushort_t)r;
}

__device__ __forceinline__ void gload16(const void* g, void* l) {
    __builtin_amdgcn_global_load_lds(
        (const __attribute__((address_space(1))) unsigned int*)g,
        (__attribute__((address_space(3))) unsigned int*)l, 16, 0, 0);
}

template<int N> __device__ __forceinline__ void waitcnt_vm() {
    asm volatile("s_waitcnt vmcnt(%0)" :: "n"(N) : "memory");
}
__device__ __forceinline__ void barrier_() { asm volatile("s_barrier" ::: "memory"); }

// ===== P = emb @ W + b_input, tiled (64x64 tiles, K=128 staged in LDS) =====
__global__ __launch_bounds__(256) void precomp_P(
    const float* __restrict__ src_emb, const float* __restrict__ tgt_emb,
    const float* __restrict__ Wf, const float* __restrict__ bf,
    const float* __restrict__ Wb, const float* __restrict__ bb,
    const float* __restrict__ Wd, const float* __restrict__ bd,
    float* __restrict__ Pf, float* __restrict__ Pb, float* __restrict__ Pd) {
    const int mat = blockIdx.z;
    const float* emb = (mat == 2) ? tgt_emb : src_emb;
    const float* W   = (mat == 0) ? Wf : (mat == 1) ? Wb : Wd;
    const float* bia = (mat == 0) ? bf : (mat == 1) ? bb : bd;
    float* P         = (mat == 0) ? Pf : (mat == 1) ? Pb : Pd;

    const int bm = blockIdx.x * 64;
    const int bn = blockIdx.y * 64;
    const int tid = threadIdx.x;
    const int tx = tid & 15;
    const int ty = tid >> 4;

    __shared__ __align__(16) float As[64][17];
    __shared__ __align__(16) float Bs[16][64];

    float acc[4][4];
#pragma unroll
    for (int i = 0; i < 4; i++)
#pragma unroll
        for (int j = 0; j < 4; j++) acc[i][j] = 0.0f;

    const int ar = tid >> 2;
    const int ak = (tid & 3) * 4;
    const int bk = tid >> 4;
    const int bc = (tid & 15) * 4;

    for (int k0 = 0; k0 < EN; k0 += 16) {
        float4 av = *reinterpret_cast<const float4*>(&emb[(bm + ar) * EN + k0 + ak]);
        As[ar][ak + 0] = av.x; As[ar][ak + 1] = av.y; As[ar][ak + 2] = av.z; As[ar][ak + 3] = av.w;
        float4 bv = *reinterpret_cast<const float4*>(&W[(k0 + bk) * GN + bn + bc]);
        *reinterpret_cast<float4*>(&Bs[bk][bc]) = bv;
        __syncthreads();
#pragma unroll
        for (int kk = 0; kk < 16; kk++) {
            float a[4];
#pragma unroll
            for (int i = 0; i < 4; i++) a[i] = As[ty * 4 + i][kk];
            float4 b4 = *reinterpret_cast<float4*>(&Bs[kk][tx * 4]);
#pragma unroll
            for (int i = 0; i < 4; i++) {
                acc[i][0] += a[i] * b4.x;
                acc[i][1] += a[i] * b4.y;
                acc[i][2] += a[i] * b4.z;
                acc[i][3] += a[i] * b4.w;
            }
        }
        __syncthreads();
    }

#pragma unroll
    for (int i = 0; i < 4; i++) {
        const int row = bm + ty * 4 + i;
#pragma unroll
        for (int j = 0; j < 4; j++) {
            const int col = bn + tx * 4 + j;
            P[(size_t)row * GN + col] = acc[i][j] + bia[col];
        }
    }
}

// Recurrent B (hi only) via LDS tile transpose, both sides coalesced.
// Bt2[mat][chunk 0..15][gcol][j 0..31] = bf16hi(U[chunk*32+j][gcol]). grid (24,16,3).
__global__ __launch_bounds__(256) void precomp_Bt2(
    const float* __restrict__ Uf, const float* __restrict__ Ub, const float* __restrict__ Ud,
    ushort_t* __restrict__ BtF, ushort_t* __restrict__ BtB, ushort_t* __restrict__ BtD) {
    const int mat = blockIdx.z;
    const float* U = (mat == 0) ? Uf : (mat == 1) ? Ub : Ud;
    ushort_t* Bt   = (mat == 0) ? BtF : (mat == 1) ? BtB : BtD;
    const int c  = blockIdx.y;          // chunk
    const int ct = blockIdx.x * 64;     // gcol tile
    const int kb = c * 32;

    __shared__ float tile[32][65];
    const int gc = threadIdx.x & 63;
    const int j0 = threadIdx.x >> 6;    // 0..3
#pragma unroll
    for (int s = 0; s < 8; ++s) {
        const int j = j0 * 8 + s;
        tile[j][gc] = U[(size_t)(kb + j) * GN + ct + gc];
    }
    __syncthreads();
    const int j  = threadIdx.x & 31;
    const int g0 = threadIdx.x >> 5;    // 0..7
#pragma unroll
    for (int p = 0; p < 8; ++p) {
        const int gcl = p * 8 + g0;
        Bt[((size_t)c * GN + ct + gcl) * 32 + j] = f2bf(tile[j][gcl]);
    }
}

// Logits B (3-term) via LDS tile transpose: Wot2[chunk 0..31][col][j]; 0..15 hi, 16..31 lo.
__global__ __launch_bounds__(256) void precomp_Wot2(
    const float* __restrict__ Wo, ushort_t* __restrict__ Wot) {
    const int c  = blockIdx.y;          // 0..31
    const int ct = blockIdx.x * 64;
    const int kb = (c < 16) ? c * 32 : (c - 16) * 32;

    __shared__ float tile[32][65];
    const int gc = threadIdx.x & 63;
    const int j0 = threadIdx.x >> 6;
#pragma unroll
    for (int s = 0; s < 8; ++s) {
        const int j = j0 * 8 + s;
        tile[j][gc] = Wo[(size_t)(kb + j) * VN + ct + gc];
    }
    __syncthreads();
    const int j  = threadIdx.x & 31;
    const int g0 = threadIdx.x >> 5;
#pragma unroll
    for (int p = 0; p < 8; ++p) {
        const int gcl = p * 8 + g0;
        float u = tile[j][gcl];
        ushort_t hi = f2bf(u);
        Wot[((size_t)c * VN + ct + gcl) * 32 + j] = (c >= 16) ? f2bf(u - bf2f(hi)) : hi;
    }
}

__global__ void dec_init(const ushort_t* __restrict__ hf, const ushort_t* __restrict__ hb,
                         ushort_t* __restrict__ hd) {
    int i = blockIdx.x * blockDim.x + threadIdx.x;
    if (i >= BN_ * HN) return;
    int row = i >> 9, col = i & (HN - 1);
    float h = bf2f(hf[(size_t)row * HC + col]) + bf2f(hf[(size_t)row * HC + HN + col])
            + bf2f(hb[(size_t)row * HC + col]) + bf2f(hb[(size_t)row * HC + HN + col]);
    ushort_t hi = f2bf(h);
    hd[(size_t)row * HC + col] = hi;
    hd[(size_t)row * HC + HN + col] = f2bf(h - bf2f(hi));
}

// ===== Encoder step: both dirs, 128 rows x 128 cols x 3 gates, 512 threads. =====
// Grid (64,4): XCD = bx%8 (64*by == 0 mod 8), dir = bx&4 (bit 2 invariant mod 8),
// rtile = (bx>>3)*4 + (bx&3) in 0..31 (128 rows each). 8 waves: wr = w>>2 (row half),
// wc = w&3 (col quarter) -> 64 rows x 32 cols x 3 gates per wave.
// Staged/step = 2 dirs x [4 bj x 8MB A + 32 rtiles x 1.5MB B] = 160 MB (half of r16).
// LDS: per buf {A-hi 128 rows, A-lo 128, B 384} x 32 shorts = 40KB; x2 = 80KB, 1 blk/CU.
// 16 chunks, B staged once; vmcnt(5) = one stage (2 A + 3 B gloads per lane).
// t==0 fast path: h_in == 0 -> skip staging/MFMA (acc=0, ho=0).
__global__ __launch_bounds__(512, 2) void enc_step(
    const ushort_t* __restrict__ hf_in, ushort_t* __restrict__ hf_out,
    const ushort_t* __restrict__ BtF, const float* __restrict__ brF, const float* __restrict__ Pf,
    const ushort_t* __restrict__ hb_in, ushort_t* __restrict__ hb_out,
    const ushort_t* __restrict__ BtB, const float* __restrict__ brB, const float* __restrict__ Pb,
    const int* __restrict__ src, int t) {
    const int bx = blockIdx.x;
    const ushort_t* hin; ushort_t* hout; const ushort_t* Bt; const float* brec; const float* P; int rev;
    if ((bx & 4) == 0) { hin = hf_in; hout = hf_out; Bt = BtF; brec = brF; P = Pf; rev = 0; }
    else               { hin = hb_in; hout = hb_out; Bt = BtB; brec = brB; P = Pb; rev = 1; }
    const int bm = ((bx >> 3) * 4 + (bx & 3)) * 128;
    const int bj = blockIdx.y * 128;
    const int tid = threadIdx.x;
    const int lane = tid & 63;
    const int w = tid >> 6;                        // 0..7
    const int wr = w >> 2, wc = w & 3;
    const int fl = lane & 15;
    const int fke = (((lane >> 4) ^ ((lane >> 1) & 3)) * 8);    // swizzled read slot
    const int lr = lane >> 2;
    const int lk = (((lane & 3) ^ ((lane >> 3) & 3)) * 8);      // swizzled global slot
    const int fq = lane >> 4;

    __shared__ __align__(16) short SM[2][640 * 32];   // A-hi 0..127, A-lo 128..255, B 256..639

    f32x4 acc[3][4][2];
#pragma unroll
    for (int g = 0; g < 3; g++)
#pragma unroll
        for (int i = 0; i < 4; i++)
#pragma unroll
            for (int n = 0; n < 2; n++) acc[g][i][n] = (f32x4){0.f, 0.f, 0.f, 0.f};

    auto stage = [&](int buf, int kc) {
        const int ah = kc * 32;
        const int al = 512 + kc * 32;
        const int r0a = w * 16;                    // 8 waves x 16 = 128 A rows
        gload16(hin + (size_t)(bm + r0a + lr) * HC + ah + lk, &SM[buf][r0a * 32]);
        gload16(hin + (size_t)(bm + r0a + lr) * HC + al + lk, &SM[buf][(128 + r0a) * 32]);
#pragma unroll
        for (int s = 0; s < 3; ++s) {
            const int r0 = w * 48 + s * 16;        // 8 waves x 48 = 384 B rows
            const int r = r0 + lr;
            const int gcol = ((r >> 7) << 9) + bj + (r & 127);   // g*512 + bj + c_local
            gload16(Bt + ((size_t)kc * GN + gcol) * 32 + lk, &SM[buf][(256 + r0) * 32]);
        }
    };
    auto compute = [&](int cur) {
        const short* Ab = &SM[cur][0];
        const short* Bb = &SM[cur][256 * 32];
        bf16x8 ah[4], al[4];
#pragma unroll
        for (int i = 0; i < 4; i++) {
            ah[i] = *(const bf16x8*)&Ab[(wr * 64 + i * 16 + fl) * 32 + fke];
            al[i] = *(const bf16x8*)&Ab[(128 + wr * 64 + i * 16 + fl) * 32 + fke];
        }
#pragma unroll
        for (int g = 0; g < 3; g++) {
#pragma unroll
            for (int n = 0; n < 2; n++) {
                bf16x8 bfr = *(const bf16x8*)&Bb[(g * 128 + wc * 32 + n * 16 + fl) * 32 + fke];
#pragma unroll
                for (int i = 0; i < 4; i++) {
                    acc[g][i][n] = __builtin_amdgcn_mfma_f32_16x16x32_bf16(ah[i], bfr, acc[g][i][n], 0, 0, 0);
                    acc[g][i][n] = __builtin_amdgcn_mfma_f32_16x16x32_bf16(al[i], bfr, acc[g][i][n], 0, 0, 0);
                }
            }
        }
    };

    if (t > 0) {   // t==0: h_in == 0 -> GEMM result is 0; skip staging entirely
        stage(0, 0);
        for (int kc = 0; kc < 16; ++kc) {
            if (kc < 15) { stage((kc + 1) & 1, kc + 1); waitcnt_vm<5>(); }
            else         { waitcnt_vm<0>(); }
            barrier_();
            compute(kc & 1);
            barrier_();
        }
    }

#pragma unroll
    for (int i = 0; i < 4; i++) {
#pragma unroll
        for (int q = 0; q < 4; q++) {
            const int row = bm + wr * 64 + i * 16 + fq * 4 + q;
            const int idx = src[row * SN + (rev ? (SN - 1 - t) : t)];
            const float* Pr = P + (size_t)idx * GN;
#pragma unroll
            for (int n = 0; n < 2; n++) {
                const int col = bj + wc * 32 + n * 16 + fl;
                float rz = acc[0][i][n][q] + brec[col];
                float rr = acc[1][i][n][q] + brec[HN + col];
                float rh = acc[2][i][n][q] + brec[2 * HN + col];
                float z = 1.f / (1.f + expf(-(Pr[col] + rz)));
                float r = 1.f / (1.f + expf(-(Pr[HN + col] + rr)));
                float hh = tanhf(Pr[2 * HN + col] + r * rh);
                float ho = (t > 0) ? (bf2f(hin[(size_t)row * HC + col]) + bf2f(hin[(size_t)row * HC + HN + col]))
                                   : 0.f;
                float hnew = z * ho + (1.f - z) * hh;
                ushort_t hib = f2bf(hnew);
                hout[(size_t)row * HC + col] = hib;
                hout[(size_t)row * HC + HN + col] = f2bf(hnew - bf2f(hib));
            }
        }
    }
}

// ===== Fused decoder step t (16 chunks, B-once) + logits of t-1 (48 chunks, 3-term). =====
// dec buffer: A-hi rows 0..63, A-lo 64..127, B 128..319 -> 20KB/buf; LDS 40KB, 3 blocks/CU.
__global__ __launch_bounds__(256, 3) void dec_fused(
    const ushort_t* __restrict__ hin, ushort_t* __restrict__ hout,
    const ushort_t* __restrict__ BtD, const float* __restrict__ brD, const float* __restrict__ Pd,
    const int* __restrict__ tgt, const ushort_t* __restrict__ Wot,
    const float* __restrict__ bo, float* __restrict__ out, int t) {
    const int bx = blockIdx.x;
    const int tid = threadIdx.x;
    const int lane = tid & 63;
    const int w = tid >> 6;
    const int fl = lane & 15;
    const int fke = (((lane >> 4) ^ ((lane >> 1) & 3)) * 8);
    const int lr = lane >> 2;
    const int lk = (((lane & 3) ^ ((lane >> 3) & 3)) * 8);
    const int fq = lane >> 4;

    __shared__ __align__(16) short SM[2][320 * 32];

    if (bx < 512) {
        const int bm = (bx & 63) * 64;
        const int bj = (bx >> 6) * 64;

        f32x4 acc[3][4];
#pragma unroll
        for (int g = 0; g < 3; g++)
#pragma unroll
            for (int i = 0; i < 4; i++) acc[g][i] = (f32x4){0.f, 0.f, 0.f, 0.f};

        auto stage = [&](int buf, int kc) {
            const int ah = kc * 32;
            const int al = 512 + kc * 32;
            const int r0a = w * 16;
            gload16(hin + (size_t)(bm + r0a + lr) * HC + ah + lk, &SM[buf][r0a * 32]);
            gload16(hin + (size_t)(bm + r0a + lr) * HC + al + lk, &SM[buf][(64 + r0a) * 32]);
#pragma unroll
            for (int s = 0; s < 3; ++s) {
                const int r0 = w * 48 + s * 16;
                const int r = r0 + lr;
                const int gcol = ((r >> 6) << 9) + bj + (r & 63);
                gload16(BtD + ((size_t)kc * GN + gcol) * 32 + lk, &SM[buf][(128 + r0) * 32]);
            }
        };
        auto compute = [&](int cur) {
            const short* Ab = &SM[cur][0];
            const short* Bb = &SM[cur][128 * 32];
            bf16x8 ah[4], al[4];
#pragma unroll
            for (int i = 0; i < 4; i++) {
                ah[i] = *(const bf16x8*)&Ab[(i * 16 + fl) * 32 + fke];
                al[i] = *(const bf16x8*)&Ab[(64 + i * 16 + fl) * 32 + fke];
            }
#pragma unroll
            for (int g = 0; g < 3; g++) {
                bf16x8 bfr = *(const bf16x8*)&Bb[(g * 64 + w * 16 + fl) * 32 + fke];
#pragma unroll
                for (int i = 0; i < 4; i++) {
                    acc[g][i] = __builtin_amdgcn_mfma_f32_16x16x32_bf16(ah[i], bfr, acc[g][i], 0, 0, 0);
                    acc[g][i] = __builtin_amdgcn_mfma_f32_16x16x32_bf16(al[i], bfr, acc[g][i], 0, 0, 0);
                }
            }
        };

        stage(0, 0);
        for (int kc = 0; kc < 16; ++kc) {
            if (kc < 15) { stage((kc + 1) & 1, kc + 1); waitcnt_vm<5>(); }
            else         { waitcnt_vm<0>(); }
            barrier_();
            compute(kc & 1);
            barrier_();
        }

#pragma unroll
        for (int i = 0; i < 4; i++) {
#pragma unroll
            for (int q = 0; q < 4; q++) {
                const int row = bm + i * 16 + fq * 4 + q;
                const int idx = (t == 0) ? BOW_ : tgt[row * TN + (t - 1)];
                const float* Pr = Pd + (size_t)idx * GN;
                const int col = bj + w * 16 + fl;
                float rz = acc[0][i][q] + brD[col];
                float rr = acc[1][i][q] + brD[HN + col];
                float rh = acc[2][i][q] + brD[2 * HN + col];
                float z = 1.f / (1.f + expf(-(Pr[col] + rz)));
                float r = 1.f / (1.f + expf(-(Pr[HN + col] + rr)));
                float hh = tanhf(Pr[2 * HN + col] + r * rh);
                float ho = bf2f(hin[(size_t)row * HC + col]) + bf2f(hin[(size_t)row * HC + HN + col]);
                float hnew = z * ho + (1.f - z) * hh;
                ushort_t hib = f2bf(hnew);
                hout[(size_t)row * HC + col] = hib;
                hout[(size_t)row * HC + HN + col] = f2bf(hnew - bf2f(hib));
            }
        }
    } else {
        if (t == 0) return;
        const int l = bx - 512;
        const int bm = (l & 63) * 64;
        const int bn = (l >> 6) * 64;

        f32x4 acc[4];
#pragma unroll
        for (int i = 0; i < 4; i++) acc[i] = (f32x4){0.f, 0.f, 0.f, 0.f};

        // 48 chunks: 0..15 Ahi x Wohi, 16..31 Alo x Wohi, 32..47 Ahi x Wolo
        auto stage = [&](int buf, int kc) {
            const int aS = (kc < 16) ? (kc * 32) : (kc < 32) ? (512 + (kc - 16) * 32) : ((kc - 32) * 32);
            const int wfix = (kc < 32) ? (kc & 15) : (16 + (kc - 32));
            const int r0 = w * 16;
            gload16(hin + (size_t)(bm + r0 + lr) * HC + aS + lk, &SM[buf][r0 * 32]);
            gload16(Wot + ((size_t)wfix * VN + bn + r0 + lr) * 32 + lk, &SM[buf][(64 + r0) * 32]);
        };
        auto compute = [&](int cur) {
            const short* Ab = &SM[cur][0];
            const short* Bb = &SM[cur][64 * 32];
            bf16x8 bfr = *(const bf16x8*)&Bb[(w * 16 + fl) * 32 + fke];
#pragma unroll
            for (int i = 0; i < 4; i++) {
                bf16x8 af = *(const bf16x8*)&Ab[(i * 16 + fl) * 32 + fke];
                acc[i] = __builtin_amdgcn_mfma_f32_16x16x32_bf16(af, bfr, acc[i], 0, 0, 0);
            }
        };

        stage(0, 0);
        for (int kc = 0; kc < 48; ++kc) {
            if (kc < 47) { stage((kc + 1) & 1, kc + 1); waitcnt_vm<2>(); }
            else         { waitcnt_vm<0>(); }
            barrier_();
            compute(kc & 1);
            barrier_();
        }

#pragma unroll
        for (int i = 0; i < 4; i++) {
#pragma unroll
            for (int q = 0; q < 4; q++) {
                const int row = bm + i * 16 + fq * 4 + q;
                const int col = bn + w * 16 + fl;
                out[(size_t)row * (TN * VN) + (t - 1) * VN + col] = acc[i][q] + bo[col];
            }
        }
    }
}

// standalone logits for the final decoder output (t = TN-1), 3-term, 48 chunks
__global__ __launch_bounds__(256) void logits_mfma(
    const ushort_t* __restrict__ hin, const ushort_t* __restrict__ Wot,
    const float* __restrict__ bo, float* __restrict__ out, int t) {
    const int bm = blockIdx.x * 64;
    const int bn = blockIdx.y * 64;
    const int tid = threadIdx.x;
    const int lane = tid & 63;
    const int w = tid >> 6;

    __shared__ __align__(16) short Asm[2][64 * 32];
    __shared__ __align__(16) short Bsm[2][64 * 32];

    f32x4 acc[4];
#pragma unroll
    for (int i = 0; i < 4; i++) acc[i] = (f32x4){0.f, 0.f, 0.f, 0.f};

    const int fl = lane & 15;
    const int fke = (((lane >> 4) ^ ((lane >> 1) & 3)) * 8);
    const int lr = lane >> 2;
    const int lk = (((lane & 3) ^ ((lane >> 3) & 3)) * 8);

    auto stage = [&](int buf, int kc) {
        const int aS = (kc < 16) ? (kc * 32) : (kc < 32) ? (512 + (kc - 16) * 32) : ((kc - 32) * 32);
        const int wfix = (kc < 32) ? (kc & 15) : (16 + (kc - 32));
        const int r0 = w * 16;
        gload16(hin + (size_t)(bm + r0 + lr) * HC + aS + lk, &Asm[buf][r0 * 32]);
        gload16(Wot + ((size_t)wfix * VN + bn + r0 + lr) * 32 + lk, &Bsm[buf][r0 * 32]);
    };
    auto compute = [&](int cur) {
        const short* Ab = Asm[cur];
        const short* Bb = Bsm[cur];
        bf16x8 bfr = *(const bf16x8*)&Bb[(w * 16 + fl) * 32 + fke];
#pragma unroll
        for (int i = 0; i < 4; i++) {
            bf16x8 af = *(const bf16x8*)&Ab[(i * 16 + fl) * 32 + fke];
            acc[i] = __builtin_amdgcn_mfma_f32_16x16x32_bf16(af, bfr, acc[i], 0, 0, 0);
        }
    };

    stage(0, 0);
    for (int kc = 0; kc < 48; ++kc) {
        if (kc < 47) { stage((kc + 1) & 1, kc + 1); waitcnt_vm<2>(); }
        else         { waitcnt_vm<0>(); }
        barrier_();
        compute(kc & 1);
        barrier_();
    }

    const int fq = lane >> 4;
#pragma unroll
    for (int i = 0; i < 4; i++) {
#pragma unroll
        for (int q = 0; q < 4; q++) {
            const int row = bm + i * 16 + fq * 4 + q;
            const int col = bn + w * 16 + fl;
            out[(size_t)row * (TN * VN) + t * VN + col] = acc[i][q] + bo[col];
        }
    }
}

extern "C" void kernel_launch(void* const* d_in, const int* in_sizes, int n_in,
                              void* d_out, int out_size, void* d_ws, size_t ws_size,
                              hipStream_t stream) {
    const int* source    = (const int*)d_in[0];
    const int* targets   = (const int*)d_in[1];
    const float* src_emb = (const float*)d_in[2];
    const float* tgt_emb = (const float*)d_in[3];
    const float* Wf = (const float*)d_in[4];
    const float* Uf = (const float*)d_in[5];
    const float* bf = (const float*)d_in[6];
    const float* Wb = (const float*)d_in[7];
    const float* Ub = (const float*)d_in[8];
    const float* bb = (const float*)d_in[9];
    const float* Wd = (const float*)d_in[10];
    const float* Ud = (const float*)d_in[11];
    const float* bd = (const float*)d_in[12];
    const float* Wo = (const float*)d_in[13];
    const float* bo = (const float*)d_in[14];
    float* out = (float*)d_out;

    char* ws = (char*)d_ws;
    ushort_t* BtF = (ushort_t*)(ws);                    // 16*1536*32*2 = 1572864 each
    ushort_t* BtB = (ushort_t*)(ws + 1572864);
    ushort_t* BtD = (ushort_t*)(ws + 2 * 1572864);
    ushort_t* Wot = (ushort_t*)(ws + 3 * 1572864);      // 32*256*32*2 = 524288
    float*    Pf  = (float*)   (ws + 3 * 1572864 + 524288);  // 3*256*1536*4 = 4718592
    float*    Pb  = Pf + VN * GN;
    float*    Pd  = Pb + VN * GN;
    char* hbase = ws + 3 * 1572864 + 524288 + 4718592;  // 4 x 4096*1024*2 = 4 x 8388608
    ushort_t* hf0 = (ushort_t*)(hbase);
    ushort_t* hf1 = (ushort_t*)(hbase + 8388608);
    ushort_t* hb0 = (ushort_t*)(hbase + 2 * 8388608);
    ushort_t* hb1 = (ushort_t*)(hbase + 3 * 8388608);

    precomp_P<<<dim3(4, 24, 3), 256, 0, stream>>>(src_emb, tgt_emb, Wf, bf, Wb, bb, Wd, bd, Pf, Pb, Pd);
    precomp_Bt2<<<dim3(24, 16, 3), 256, 0, stream>>>(Uf, Ub, Ud, BtF, BtB, BtD);
    precomp_Wot2<<<dim3(4, 32), 256, 0, stream>>>(Wo, Wot);

    // encoder: grid (64,4): XCD 0-3 fwd / 4-7 bwd, 128x128 tiles, 512 threads.
    // t==0 reads no h state (fast path), so hf0/hb0 need no zero-init.
    for (int t = 0; t < SN; t++) {
        const ushort_t* hfi = (t & 1) ? hf1 : hf0; ushort_t* hfo = (t & 1) ? hf0 : hf1;
        const ushort_t* hbi = (t & 1) ? hb1 : hb0; ushort_t* hbo = (t & 1) ? hb0 : hb1;
        enc_step<<<dim3(64, 4), 512, 0, stream>>>(
            hfi, hfo, BtF, bf + GN, Pf,
            hbi, hbo, BtB, bb + GN, Pb,
            source, t);
    }
    dec_init<<<(BN_ * HN + 255) / 256, 256, 0, stream>>>(hf0, hb0, hb1);

    // fused decoder step t + logits(t-1); ping-pong hb1 <-> hf1
    for (int t = 0; t < TN; t++) {
        const ushort_t* hdi = (t & 1) ? hf1 : hb1; ushort_t* hdo = (t & 1) ? hb1 : hf1;
        dec_fused<<<768, 256, 0, stream>>>(
            hdi, hdo, BtD, bd + GN, Pd, targets, Wot, bo, out, t);
    }
    // final logits for t = 23 output (hdo of t=23 is hb1 since 23 is odd)
    logits_mfma<<<dim3(64, 4), 256, 0, stream>>>(hb1, Wot, bo, out, TN - 1);
}

// Round 18
// 1857.275 us; speedup vs baseline: 1.0674x; 1.0674x over previous
//
#include <hip/hip_runtime.h>
#include <math.h>

typedef unsigned short ushort_t;
typedef short bf16x8 __attribute__((ext_vector_type(8)));   // 8 bf16 = 4 VGPRs (MFMA A/B frag)
typedef float f32x4 __attribute__((ext_vector_type(4)));    // MFMA C/D frag

#define BN_ 4096
#define SN 24
#define TN 24
#define EN 128
#define HN 512
#define GN 1536
#define VN 256
#define BOW_ 1
#define HC 1024   // hcat row stride: [hi(512) | lo(512)]
// Recurrent GEMMs: 2-term split, 16 chunks of BK=32, B STAGED ONCE per chunk:
//   per kc: stage {A-hi(k=kc*32), A-lo(k=512+kc*32), B chunk kc}; acc += Ahi x B + Alo x B.
// Logits: 3-term split, 16 chunks staging {Ahi, Alo, Wohi(kc), Wolo(16+kc)} once:
//   acc += Ahi x Wh + Alo x Wh + Ahi x Wl per chunk.

__device__ __forceinline__ float bf2f(ushort_t u) {
    union { unsigned int i; float f; } v; v.i = ((unsigned int)u) << 16; return v.f;
}
__device__ __forceinline__ ushort_t f2bf(float f) {  // round-to-nearest-even
    union { float f; unsigned int i; } v; v.f = f;
    unsigned int r = (v.i + 0x7FFFu + ((v.i >> 16) & 1u)) >> 16;
    return (ushort_t)r;
}

__device__ __forceinline__ void gload16(const void* g, void* l) {
    __builtin_amdgcn_global_load_lds(
        (const __attribute__((address_space(1))) unsigned int*)g,
        (__attribute__((address_space(3))) unsigned int*)l, 16, 0, 0);
}

template<int N> __device__ __forceinline__ void waitcnt_vm() {
    asm volatile("s_waitcnt vmcnt(%0)" :: "n"(N) : "memory");
}
__device__ __forceinline__ void barrier_() { asm volatile("s_barrier" ::: "memory"); }

// ===== P = emb @ W + b_input, tiled (64x64 tiles, K=128 staged in LDS) =====
__global__ __launch_bounds__(256) void precomp_P(
    const float* __restrict__ src_emb, const float* __restrict__ tgt_emb,
    const float* __restrict__ Wf, const float* __restrict__ bf,
    const float* __restrict__ Wb, const float* __restrict__ bb,
    const float* __restrict__ Wd, const float* __restrict__ bd,
    float* __restrict__ Pf, float* __restrict__ Pb, float* __restrict__ Pd) {
    const int mat = blockIdx.z;
    const float* emb = (mat == 2) ? tgt_emb : src_emb;
    const float* W   = (mat == 0) ? Wf : (mat == 1) ? Wb : Wd;
    const float* bia = (mat == 0) ? bf : (mat == 1) ? bb : bd;
    float* P         = (mat == 0) ? Pf : (mat == 1) ? Pb : Pd;

    const int bm = blockIdx.x * 64;
    const int bn = blockIdx.y * 64;
    const int tid = threadIdx.x;
    const int tx = tid & 15;
    const int ty = tid >> 4;

    __shared__ __align__(16) float As[64][17];
    __shared__ __align__(16) float Bs[16][64];

    float acc[4][4];
#pragma unroll
    for (int i = 0; i < 4; i++)
#pragma unroll
        for (int j = 0; j < 4; j++) acc[i][j] = 0.0f;

    const int ar = tid >> 2;
    const int ak = (tid & 3) * 4;
    const int bk = tid >> 4;
    const int bc = (tid & 15) * 4;

    for (int k0 = 0; k0 < EN; k0 += 16) {
        float4 av = *reinterpret_cast<const float4*>(&emb[(bm + ar) * EN + k0 + ak]);
        As[ar][ak + 0] = av.x; As[ar][ak + 1] = av.y; As[ar][ak + 2] = av.z; As[ar][ak + 3] = av.w;
        float4 bv = *reinterpret_cast<const float4*>(&W[(k0 + bk) * GN + bn + bc]);
        *reinterpret_cast<float4*>(&Bs[bk][bc]) = bv;
        __syncthreads();
#pragma unroll
        for (int kk = 0; kk < 16; kk++) {
            float a[4];
#pragma unroll
            for (int i = 0; i < 4; i++) a[i] = As[ty * 4 + i][kk];
            float4 b4 = *reinterpret_cast<float4*>(&Bs[kk][tx * 4]);
#pragma unroll
            for (int i = 0; i < 4; i++) {
                acc[i][0] += a[i] * b4.x;
                acc[i][1] += a[i] * b4.y;
                acc[i][2] += a[i] * b4.z;
                acc[i][3] += a[i] * b4.w;
            }
        }
        __syncthreads();
    }

#pragma unroll
    for (int i = 0; i < 4; i++) {
        const int row = bm + ty * 4 + i;
#pragma unroll
        for (int j = 0; j < 4; j++) {
            const int col = bn + tx * 4 + j;
            P[(size_t)row * GN + col] = acc[i][j] + bia[col];
        }
    }
}

// Recurrent B (hi only) via LDS tile transpose, both sides coalesced.
// Bt2[mat][chunk 0..15][gcol][j 0..31] = bf16hi(U[chunk*32+j][gcol]). grid (24,16,3).
__global__ __launch_bounds__(256) void precomp_Bt2(
    const float* __restrict__ Uf, const float* __restrict__ Ub, const float* __restrict__ Ud,
    ushort_t* __restrict__ BtF, ushort_t* __restrict__ BtB, ushort_t* __restrict__ BtD) {
    const int mat = blockIdx.z;
    const float* U = (mat == 0) ? Uf : (mat == 1) ? Ub : Ud;
    ushort_t* Bt   = (mat == 0) ? BtF : (mat == 1) ? BtB : BtD;
    const int c  = blockIdx.y;          // chunk
    const int ct = blockIdx.x * 64;     // gcol tile
    const int kb = c * 32;

    __shared__ float tile[32][65];
    const int gc = threadIdx.x & 63;
    const int j0 = threadIdx.x >> 6;    // 0..3
#pragma unroll
    for (int s = 0; s < 8; ++s) {
        const int j = j0 * 8 + s;
        tile[j][gc] = U[(size_t)(kb + j) * GN + ct + gc];
    }
    __syncthreads();
    const int j  = threadIdx.x & 31;
    const int g0 = threadIdx.x >> 5;    // 0..7
#pragma unroll
    for (int p = 0; p < 8; ++p) {
        const int gcl = p * 8 + g0;
        Bt[((size_t)c * GN + ct + gcl) * 32 + j] = f2bf(tile[j][gcl]);
    }
}

// Logits B (3-term) via LDS tile transpose: Wot2[chunk 0..31][col][j]; 0..15 hi, 16..31 lo.
__global__ __launch_bounds__(256) void precomp_Wot2(
    const float* __restrict__ Wo, ushort_t* __restrict__ Wot) {
    const int c  = blockIdx.y;          // 0..31
    const int ct = blockIdx.x * 64;
    const int kb = (c < 16) ? c * 32 : (c - 16) * 32;

    __shared__ float tile[32][65];
    const int gc = threadIdx.x & 63;
    const int j0 = threadIdx.x >> 6;
#pragma unroll
    for (int s = 0; s < 8; ++s) {
        const int j = j0 * 8 + s;
        tile[j][gc] = Wo[(size_t)(kb + j) * VN + ct + gc];
    }
    __syncthreads();
    const int j  = threadIdx.x & 31;
    const int g0 = threadIdx.x >> 5;
#pragma unroll
    for (int p = 0; p < 8; ++p) {
        const int gcl = p * 8 + g0;
        float u = tile[j][gcl];
        ushort_t hi = f2bf(u);
        Wot[((size_t)c * VN + ct + gcl) * 32 + j] = (c >= 16) ? f2bf(u - bf2f(hi)) : hi;
    }
}

__global__ void dec_init(const ushort_t* __restrict__ hf, const ushort_t* __restrict__ hb,
                         ushort_t* __restrict__ hd) {
    int i = blockIdx.x * blockDim.x + threadIdx.x;
    if (i >= BN_ * HN) return;
    int row = i >> 9, col = i & (HN - 1);
    float h = bf2f(hf[(size_t)row * HC + col]) + bf2f(hf[(size_t)row * HC + HN + col])
            + bf2f(hb[(size_t)row * HC + col]) + bf2f(hb[(size_t)row * HC + HN + col]);
    ushort_t hi = f2bf(h);
    hd[(size_t)row * HC + col] = hi;
    hd[(size_t)row * HC + HN + col] = f2bf(h - bf2f(hi));
}

// ===== Encoder step (r16 config): both dirs, MT=64, 4 waves of 64x16x3gates. =====
// Grid (128,8): XCD = bx%8, dir = bx&4, rtile = (bx>>3)*4 + (bx&3). 4 blocks/CU.
// 16 chunks; per chunk stage {A-hi 4K, A-lo 4K, B 12K} (B once). vmcnt(5).
// t==0 fast path: h_in == 0 -> skip staging/MFMA (acc=0, ho=0).
__global__ __launch_bounds__(256, 4) void enc_step(
    const ushort_t* __restrict__ hf_in, ushort_t* __restrict__ hf_out,
    const ushort_t* __restrict__ BtF, const float* __restrict__ brF, const float* __restrict__ Pf,
    const ushort_t* __restrict__ hb_in, ushort_t* __restrict__ hb_out,
    const ushort_t* __restrict__ BtB, const float* __restrict__ brB, const float* __restrict__ Pb,
    const int* __restrict__ src, int t) {
    const int bx = blockIdx.x;
    const ushort_t* hin; ushort_t* hout; const ushort_t* Bt; const float* brec; const float* P; int rev;
    if ((bx & 4) == 0) { hin = hf_in; hout = hf_out; Bt = BtF; brec = brF; P = Pf; rev = 0; }
    else               { hin = hb_in; hout = hb_out; Bt = BtB; brec = brB; P = Pb; rev = 1; }
    const int bm = ((bx >> 3) * 4 + (bx & 3)) * 64;
    const int bj = blockIdx.y * 64;
    const int tid = threadIdx.x;
    const int lane = tid & 63;
    const int w = tid >> 6;
    const int fl = lane & 15;
    const int fke = (((lane >> 4) ^ ((lane >> 1) & 3)) * 8);    // swizzled read slot
    const int lr = lane >> 2;
    const int lk = (((lane & 3) ^ ((lane >> 3) & 3)) * 8);      // swizzled global slot
    const int fq = lane >> 4;

    __shared__ __align__(16) short SM[2][320 * 32];   // A-hi 0..63, A-lo 64..127, B 128..319

    f32x4 acc[3][4];
#pragma unroll
    for (int g = 0; g < 3; g++)
#pragma unroll
        for (int i = 0; i < 4; i++) acc[g][i] = (f32x4){0.f, 0.f, 0.f, 0.f};

    auto stage = [&](int buf, int kc) {
        const int ah = kc * 32;
        const int al = 512 + kc * 32;
        const int r0a = w * 16;
        gload16(hin + (size_t)(bm + r0a + lr) * HC + ah + lk, &SM[buf][r0a * 32]);
        gload16(hin + (size_t)(bm + r0a + lr) * HC + al + lk, &SM[buf][(64 + r0a) * 32]);
#pragma unroll
        for (int s = 0; s < 3; ++s) {
            const int r0 = w * 48 + s * 16;
            const int r = r0 + lr;
            const int gcol = ((r >> 6) << 9) + bj + (r & 63);
            gload16(Bt + ((size_t)kc * GN + gcol) * 32 + lk, &SM[buf][(128 + r0) * 32]);
        }
    };
    auto compute = [&](int cur) {
        const short* Ab = &SM[cur][0];
        const short* Bb = &SM[cur][128 * 32];
        bf16x8 ah[4], al[4];
#pragma unroll
        for (int i = 0; i < 4; i++) {
            ah[i] = *(const bf16x8*)&Ab[(i * 16 + fl) * 32 + fke];
            al[i] = *(const bf16x8*)&Ab[(64 + i * 16 + fl) * 32 + fke];
        }
#pragma unroll
        for (int g = 0; g < 3; g++) {
            bf16x8 bfr = *(const bf16x8*)&Bb[(g * 64 + w * 16 + fl) * 32 + fke];
#pragma unroll
            for (int i = 0; i < 4; i++) {
                acc[g][i] = __builtin_amdgcn_mfma_f32_16x16x32_bf16(ah[i], bfr, acc[g][i], 0, 0, 0);
                acc[g][i] = __builtin_amdgcn_mfma_f32_16x16x32_bf16(al[i], bfr, acc[g][i], 0, 0, 0);
            }
        }
    };

    if (t > 0) {   // t==0: h_in == 0 -> GEMM result is 0; skip staging entirely
        stage(0, 0);
        for (int kc = 0; kc < 16; ++kc) {
            if (kc < 15) { stage((kc + 1) & 1, kc + 1); waitcnt_vm<5>(); }
            else         { waitcnt_vm<0>(); }
            barrier_();
            compute(kc & 1);
            barrier_();
        }
    }

#pragma unroll
    for (int i = 0; i < 4; i++) {
#pragma unroll
        for (int q = 0; q < 4; q++) {
            const int row = bm + i * 16 + fq * 4 + q;
            const int idx = src[row * SN + (rev ? (SN - 1 - t) : t)];
            const float* Pr = P + (size_t)idx * GN;
            const int col = bj + w * 16 + fl;
            float rz = acc[0][i][q] + brec[col];
            float rr = acc[1][i][q] + brec[HN + col];
            float rh = acc[2][i][q] + brec[2 * HN + col];
            float z = 1.f / (1.f + expf(-(Pr[col] + rz)));
            float r = 1.f / (1.f + expf(-(Pr[HN + col] + rr)));
            float hh = tanhf(Pr[2 * HN + col] + r * rh);
            float ho = (t > 0) ? (bf2f(hin[(size_t)row * HC + col]) + bf2f(hin[(size_t)row * HC + HN + col]))
                               : 0.f;
            float hnew = z * ho + (1.f - z) * hh;
            ushort_t hib = f2bf(hnew);
            hout[(size_t)row * HC + col] = hib;
            hout[(size_t)row * HC + HN + col] = f2bf(hnew - bf2f(hib));
        }
    }
}

// ===== Fused decoder step t (16 chunks, B-once) + logits of t-1 (16 chunks, all-once). =====
// dec buffer: A-hi 0..63, A-lo 64..127, B 128..319 -> 20KB/buf.
// logits buffer: A-hi 0..63, A-lo 64..127, Wh 128..191, Wl 192..255 -> 16KB/buf.
// LDS 40KB, 3 blocks/CU.
__global__ __launch_bounds__(256, 3) void dec_fused(
    const ushort_t* __restrict__ hin, ushort_t* __restrict__ hout,
    const ushort_t* __restrict__ BtD, const float* __restrict__ brD, const float* __restrict__ Pd,
    const int* __restrict__ tgt, const ushort_t* __restrict__ Wot,
    const float* __restrict__ bo, float* __restrict__ out, int t) {
    const int bx = blockIdx.x;
    const int tid = threadIdx.x;
    const int lane = tid & 63;
    const int w = tid >> 6;
    const int fl = lane & 15;
    const int fke = (((lane >> 4) ^ ((lane >> 1) & 3)) * 8);
    const int lr = lane >> 2;
    const int lk = (((lane & 3) ^ ((lane >> 3) & 3)) * 8);
    const int fq = lane >> 4;

    __shared__ __align__(16) short SM[2][320 * 32];

    if (bx < 512) {
        const int bm = (bx & 63) * 64;
        const int bj = (bx >> 6) * 64;

        f32x4 acc[3][4];
#pragma unroll
        for (int g = 0; g < 3; g++)
#pragma unroll
            for (int i = 0; i < 4; i++) acc[g][i] = (f32x4){0.f, 0.f, 0.f, 0.f};

        auto stage = [&](int buf, int kc) {
            const int ah = kc * 32;
            const int al = 512 + kc * 32;
            const int r0a = w * 16;
            gload16(hin + (size_t)(bm + r0a + lr) * HC + ah + lk, &SM[buf][r0a * 32]);
            gload16(hin + (size_t)(bm + r0a + lr) * HC + al + lk, &SM[buf][(64 + r0a) * 32]);
#pragma unroll
            for (int s = 0; s < 3; ++s) {
                const int r0 = w * 48 + s * 16;
                const int r = r0 + lr;
                const int gcol = ((r >> 6) << 9) + bj + (r & 63);
                gload16(BtD + ((size_t)kc * GN + gcol) * 32 + lk, &SM[buf][(128 + r0) * 32]);
            }
        };
        auto compute = [&](int cur) {
            const short* Ab = &SM[cur][0];
            const short* Bb = &SM[cur][128 * 32];
            bf16x8 ah[4], al[4];
#pragma unroll
            for (int i = 0; i < 4; i++) {
                ah[i] = *(const bf16x8*)&Ab[(i * 16 + fl) * 32 + fke];
                al[i] = *(const bf16x8*)&Ab[(64 + i * 16 + fl) * 32 + fke];
            }
#pragma unroll
            for (int g = 0; g < 3; g++) {
                bf16x8 bfr = *(const bf16x8*)&Bb[(g * 64 + w * 16 + fl) * 32 + fke];
#pragma unroll
                for (int i = 0; i < 4; i++) {
                    acc[g][i] = __builtin_amdgcn_mfma_f32_16x16x32_bf16(ah[i], bfr, acc[g][i], 0, 0, 0);
                    acc[g][i] = __builtin_amdgcn_mfma_f32_16x16x32_bf16(al[i], bfr, acc[g][i], 0, 0, 0);
                }
            }
        };

        stage(0, 0);
        for (int kc = 0; kc < 16; ++kc) {
            if (kc < 15) { stage((kc + 1) & 1, kc + 1); waitcnt_vm<5>(); }
            else         { waitcnt_vm<0>(); }
            barrier_();
            compute(kc & 1);
            barrier_();
        }

#pragma unroll
        for (int i = 0; i < 4; i++) {
#pragma unroll
            for (int q = 0; q < 4; q++) {
                const int row = bm + i * 16 + fq * 4 + q;
                const int idx = (t == 0) ? BOW_ : tgt[row * TN + (t - 1)];
                const float* Pr = Pd + (size_t)idx * GN;
                const int col = bj + w * 16 + fl;
                float rz = acc[0][i][q] + brD[col];
                float rr = acc[1][i][q] + brD[HN + col];
                float rh = acc[2][i][q] + brD[2 * HN + col];
                float z = 1.f / (1.f + expf(-(Pr[col] + rz)));
                float r = 1.f / (1.f + expf(-(Pr[HN + col] + rr)));
                float hh = tanhf(Pr[2 * HN + col] + r * rh);
                float ho = bf2f(hin[(size_t)row * HC + col]) + bf2f(hin[(size_t)row * HC + HN + col]);
                float hnew = z * ho + (1.f - z) * hh;
                ushort_t hib = f2bf(hnew);
                hout[(size_t)row * HC + col] = hib;
                hout[(size_t)row * HC + HN + col] = f2bf(hnew - bf2f(hib));
            }
        }
    } else {
        if (t == 0) return;
        const int l = bx - 512;
        const int bm = (l & 63) * 64;
        const int bn = (l >> 6) * 64;

        f32x4 acc[4];
#pragma unroll
        for (int i = 0; i < 4; i++) acc[i] = (f32x4){0.f, 0.f, 0.f, 0.f};

        // 16 chunks; per chunk stage {Ahi, Alo, Wohi(kc), Wolo(16+kc)} once;
        // acc += Ahi x Wh + Alo x Wh + Ahi x Wl.
        auto stage = [&](int buf, int kc) {
            const int ah = kc * 32;
            const int al = 512 + kc * 32;
            const int r0 = w * 16;
            gload16(hin + (size_t)(bm + r0 + lr) * HC + ah + lk, &SM[buf][r0 * 32]);
            gload16(hin + (size_t)(bm + r0 + lr) * HC + al + lk, &SM[buf][(64 + r0) * 32]);
            gload16(Wot + ((size_t)kc * VN + bn + r0 + lr) * 32 + lk, &SM[buf][(128 + r0) * 32]);
            gload16(Wot + ((size_t)(16 + kc) * VN + bn + r0 + lr) * 32 + lk, &SM[buf][(192 + r0) * 32]);
        };
        auto compute = [&](int cur) {
            const short* Ab = &SM[cur][0];
            bf16x8 wh = *(const bf16x8*)&SM[cur][(128 + w * 16 + fl) * 32 + fke];
            bf16x8 wl = *(const bf16x8*)&SM[cur][(192 + w * 16 + fl) * 32 + fke];
#pragma unroll
            for (int i = 0; i < 4; i++) {
                bf16x8 ah = *(const bf16x8*)&Ab[(i * 16 + fl) * 32 + fke];
                bf16x8 al = *(const bf16x8*)&Ab[(64 + i * 16 + fl) * 32 + fke];
                acc[i] = __builtin_amdgcn_mfma_f32_16x16x32_bf16(ah, wh, acc[i], 0, 0, 0);
                acc[i] = __builtin_amdgcn_mfma_f32_16x16x32_bf16(al, wh, acc[i], 0, 0, 0);
                acc[i] = __builtin_amdgcn_mfma_f32_16x16x32_bf16(ah, wl, acc[i], 0, 0, 0);
            }
        };

        stage(0, 0);
        for (int kc = 0; kc < 16; ++kc) {
            if (kc < 15) { stage((kc + 1) & 1, kc + 1); waitcnt_vm<4>(); }
            else         { waitcnt_vm<0>(); }
            barrier_();
            compute(kc & 1);
            barrier_();
        }

#pragma unroll
        for (int i = 0; i < 4; i++) {
#pragma unroll
            for (int q = 0; q < 4; q++) {
                const int row = bm + i * 16 + fq * 4 + q;
                const int col = bn + w * 16 + fl;
                out[(size_t)row * (TN * VN) + (t - 1) * VN + col] = acc[i][q] + bo[col];
            }
        }
    }
}

// standalone logits for the final decoder output (t = TN-1), 16 chunks all-once
__global__ __launch_bounds__(256) void logits_mfma(
    const ushort_t* __restrict__ hin, const ushort_t* __restrict__ Wot,
    const float* __restrict__ bo, float* __restrict__ out, int t) {
    const int bm = blockIdx.x * 64;
    const int bn = blockIdx.y * 64;
    const int tid = threadIdx.x;
    const int lane = tid & 63;
    const int w = tid >> 6;

    __shared__ __align__(16) short SM[2][256 * 32];

    f32x4 acc[4];
#pragma unroll
    for (int i = 0; i < 4; i++) acc[i] = (f32x4){0.f, 0.f, 0.f, 0.f};

    const int fl = lane & 15;
    const int fke = (((lane >> 4) ^ ((lane >> 1) & 3)) * 8);
    const int lr = lane >> 2;
    const int lk = (((lane & 3) ^ ((lane >> 3) & 3)) * 8);

    auto stage = [&](int buf, int kc) {
        const int ah = kc * 32;
        const int al = 512 + kc * 32;
        const int r0 = w * 16;
        gload16(hin + (size_t)(bm + r0 + lr) * HC + ah + lk, &SM[buf][r0 * 32]);
        gload16(hin + (size_t)(bm + r0 + lr) * HC + al + lk, &SM[buf][(64 + r0) * 32]);
        gload16(Wot + ((size_t)kc * VN + bn + r0 + lr) * 32 + lk, &SM[buf][(128 + r0) * 32]);
        gload16(Wot + ((size_t)(16 + kc) * VN + bn + r0 + lr) * 32 + lk, &SM[buf][(192 + r0) * 32]);
    };
    auto compute = [&](int cur) {
        const short* Ab = &SM[cur][0];
        bf16x8 wh = *(const bf16x8*)&SM[cur][(128 + w * 16 + fl) * 32 + fke];
        bf16x8 wl = *(const bf16x8*)&SM[cur][(192 + w * 16 + fl) * 32 + fke];
#pragma unroll
        for (int i = 0; i < 4; i++) {
            bf16x8 ah = *(const bf16x8*)&Ab[(i * 16 + fl) * 32 + fke];
            bf16x8 al = *(const bf16x8*)&Ab[(64 + i * 16 + fl) * 32 + fke];
            acc[i] = __builtin_amdgcn_mfma_f32_16x16x32_bf16(ah, wh, acc[i], 0, 0, 0);
            acc[i] = __builtin_amdgcn_mfma_f32_16x16x32_bf16(al, wh, acc[i], 0, 0, 0);
            acc[i] = __builtin_amdgcn_mfma_f32_16x16x32_bf16(ah, wl, acc[i], 0, 0, 0);
        }
    };

    stage(0, 0);
    for (int kc = 0; kc < 16; ++kc) {
        if (kc < 15) { stage((kc + 1) & 1, kc + 1); waitcnt_vm<4>(); }
        else         { waitcnt_vm<0>(); }
        barrier_();
        compute(kc & 1);
        barrier_();
    }

    const int fq = lane >> 4;
#pragma unroll
    for (int i = 0; i < 4; i++) {
#pragma unroll
        for (int q = 0; q < 4; q++) {
            const int row = bm + i * 16 + fq * 4 + q;
            const int col = bn + w * 16 + fl;
            out[(size_t)row * (TN * VN) + t * VN + col] = acc[i][q] + bo[col];
        }
    }
}

extern "C" void kernel_launch(void* const* d_in, const int* in_sizes, int n_in,
                              void* d_out, int out_size, void* d_ws, size_t ws_size,
                              hipStream_t stream) {
    const int* source    = (const int*)d_in[0];
    const int* targets   = (const int*)d_in[1];
    const float* src_emb = (const float*)d_in[2];
    const float* tgt_emb = (const float*)d_in[3];
    const float* Wf = (const float*)d_in[4];
    const float* Uf = (const float*)d_in[5];
    const float* bf = (const float*)d_in[6];
    const float* Wb = (const float*)d_in[7];
    const float* Ub = (const float*)d_in[8];
    const float* bb = (const float*)d_in[9];
    const float* Wd = (const float*)d_in[10];
    const float* Ud = (const float*)d_in[11];
    const float* bd = (const float*)d_in[12];
    const float* Wo = (const float*)d_in[13];
    const float* bo = (const float*)d_in[14];
    float* out = (float*)d_out;

    char* ws = (char*)d_ws;
    ushort_t* BtF = (ushort_t*)(ws);                    // 16*1536*32*2 = 1572864 each
    ushort_t* BtB = (ushort_t*)(ws + 1572864);
    ushort_t* BtD = (ushort_t*)(ws + 2 * 1572864);
    ushort_t* Wot = (ushort_t*)(ws + 3 * 1572864);      // 32*256*32*2 = 524288
    float*    Pf  = (float*)   (ws + 3 * 1572864 + 524288);  // 3*256*1536*4 = 4718592
    float*    Pb  = Pf + VN * GN;
    float*    Pd  = Pb + VN * GN;
    char* hbase = ws + 3 * 1572864 + 524288 + 4718592;  // 4 x 4096*1024*2 = 4 x 8388608
    ushort_t* hf0 = (ushort_t*)(hbase);
    ushort_t* hf1 = (ushort_t*)(hbase + 8388608);
    ushort_t* hb0 = (ushort_t*)(hbase + 2 * 8388608);
    ushort_t* hb1 = (ushort_t*)(hbase + 3 * 8388608);

    precomp_P<<<dim3(4, 24, 3), 256, 0, stream>>>(src_emb, tgt_emb, Wf, bf, Wb, bb, Wd, bd, Pf, Pb, Pd);
    precomp_Bt2<<<dim3(24, 16, 3), 256, 0, stream>>>(Uf, Ub, Ud, BtF, BtB, BtD);
    precomp_Wot2<<<dim3(4, 32), 256, 0, stream>>>(Wo, Wot);

    // encoder: grid (128,8): XCD 0-3 fwd / 4-7 bwd, 64-row tiles, 4 blocks/CU.
    // t==0 reads no h state (fast path), so hf0/hb0 need no zero-init.
    for (int t = 0; t < SN; t++) {
        const ushort_t* hfi = (t & 1) ? hf1 : hf0; ushort_t* hfo = (t & 1) ? hf0 : hf1;
        const ushort_t* hbi = (t & 1) ? hb1 : hb0; ushort_t* hbo = (t & 1) ? hb0 : hb1;
        enc_step<<<dim3(128, 8), 256, 0, stream>>>(
            hfi, hfo, BtF, bf + GN, Pf,
            hbi, hbo, BtB, bb + GN, Pb,
            source, t);
    }
    dec_init<<<(BN_ * HN + 255) / 256, 256, 0, stream>>>(hf0, hb0, hb1);

    // fused decoder step t + logits(t-1); ping-pong hb1 <-> hf1
    for (int t = 0; t < TN; t++) {
        const ushort_t* hdi = (t & 1) ? hf1 : hb1; ushort_t* hdo = (t & 1) ? hb1 : hf1;
        dec_fused<<<768, 256, 0, stream>>>(
            hdi, hdo, BtD, bd + GN, Pd, targets, Wot, bo, out, t);
    }
    // final logits for t = 23 output (hdo of t=23 is hb1 since 23 is odd)
    logits_mfma<<<dim3(64, 4), 256, 0, stream>>>(hb1, Wot, bo, out, TN - 1);
}

// Round 19
// 1550.896 us; speedup vs baseline: 1.2783x; 1.1975x over previous
//
#include <hip/hip_runtime.h>
#include <math.h>

typedef unsigned short ushort_t;
typedef short bf16x8 __attribute__((ext_vector_type(8)));   // 8 bf16 = 4 VGPRs (MFMA A/B frag)
typedef float f32x4 __attribute__((ext_vector_type(4)));    // MFMA C/D frag

#define BN_ 4096
#define SN 24
#define TN 24
#define EN 128
#define HN 512
#define GN 1536
#define VN 256
#define BOW_ 1
#define HC 1024   // hcat row stride: [hi(512) | lo(512)]
// Recurrence GEMMs (enc/dec): 1-term bf16(h) x bf16(U), 16 chunks of BK=32.
//   h-lo is kept ONLY for (a) the exact z*h_old leak path and (b) the logits A-operand.
// Logits: 3-term, 16 chunks staging {Ahi, Alo, Wohi(kc), Wolo(16+kc)} once:
//   acc += Ahi x Wh + Alo x Wh + Ahi x Wl per chunk.

__device__ __forceinline__ float bf2f(ushort_t u) {
    union { unsigned int i; float f; } v; v.i = ((unsigned int)u) << 16; return v.f;
}
__device__ __forceinline__ ushort_t f2bf(float f) {  // round-to-nearest-even
    union { float f; unsigned int i; } v; v.f = f;
    unsigned int r = (v.i + 0x7FFFu + ((v.i >> 16) & 1u)) >> 16;
    return (ushort_t)r;
}

__device__ __forceinline__ void gload16(const void* g, void* l) {
    __builtin_amdgcn_global_load_lds(
        (const __attribute__((address_space(1))) unsigned int*)g,
        (__attribute__((address_space(3))) unsigned int*)l, 16, 0, 0);
}

template<int N> __device__ __forceinline__ void waitcnt_vm() {
    asm volatile("s_waitcnt vmcnt(%0)" :: "n"(N) : "memory");
}
__device__ __forceinline__ void barrier_() { asm volatile("s_barrier" ::: "memory"); }

// ===== P = emb @ W + b_input, tiled (64x64 tiles, K=128 staged in LDS) =====
__global__ __launch_bounds__(256) void precomp_P(
    const float* __restrict__ src_emb, const float* __restrict__ tgt_emb,
    const float* __restrict__ Wf, const float* __restrict__ bf,
    const float* __restrict__ Wb, const float* __restrict__ bb,
    const float* __restrict__ Wd, const float* __restrict__ bd,
    float* __restrict__ Pf, float* __restrict__ Pb, float* __restrict__ Pd) {
    const int mat = blockIdx.z;
    const float* emb = (mat == 2) ? tgt_emb : src_emb;
    const float* W   = (mat == 0) ? Wf : (mat == 1) ? Wb : Wd;
    const float* bia = (mat == 0) ? bf : (mat == 1) ? bb : bd;
    float* P         = (mat == 0) ? Pf : (mat == 1) ? Pb : Pd;

    const int bm = blockIdx.x * 64;
    const int bn = blockIdx.y * 64;
    const int tid = threadIdx.x;
    const int tx = tid & 15;
    const int ty = tid >> 4;

    __shared__ __align__(16) float As[64][17];
    __shared__ __align__(16) float Bs[16][64];

    float acc[4][4];
#pragma unroll
    for (int i = 0; i < 4; i++)
#pragma unroll
        for (int j = 0; j < 4; j++) acc[i][j] = 0.0f;

    const int ar = tid >> 2;
    const int ak = (tid & 3) * 4;
    const int bk = tid >> 4;
    const int bc = (tid & 15) * 4;

    for (int k0 = 0; k0 < EN; k0 += 16) {
        float4 av = *reinterpret_cast<const float4*>(&emb[(bm + ar) * EN + k0 + ak]);
        As[ar][ak + 0] = av.x; As[ar][ak + 1] = av.y; As[ar][ak + 2] = av.z; As[ar][ak + 3] = av.w;
        float4 bv = *reinterpret_cast<const float4*>(&W[(k0 + bk) * GN + bn + bc]);
        *reinterpret_cast<float4*>(&Bs[bk][bc]) = bv;
        __syncthreads();
#pragma unroll
        for (int kk = 0; kk < 16; kk++) {
            float a[4];
#pragma unroll
            for (int i = 0; i < 4; i++) a[i] = As[ty * 4 + i][kk];
            float4 b4 = *reinterpret_cast<float4*>(&Bs[kk][tx * 4]);
#pragma unroll
            for (int i = 0; i < 4; i++) {
                acc[i][0] += a[i] * b4.x;
                acc[i][1] += a[i] * b4.y;
                acc[i][2] += a[i] * b4.z;
                acc[i][3] += a[i] * b4.w;
            }
        }
        __syncthreads();
    }

#pragma unroll
    for (int i = 0; i < 4; i++) {
        const int row = bm + ty * 4 + i;
#pragma unroll
        for (int j = 0; j < 4; j++) {
            const int col = bn + tx * 4 + j;
            P[(size_t)row * GN + col] = acc[i][j] + bia[col];
        }
    }
}

// Recurrent B (hi only) via LDS tile transpose, both sides coalesced.
// Bt2[mat][chunk 0..15][gcol][j 0..31] = bf16hi(U[chunk*32+j][gcol]). grid (24,16,3).
__global__ __launch_bounds__(256) void precomp_Bt2(
    const float* __restrict__ Uf, const float* __restrict__ Ub, const float* __restrict__ Ud,
    ushort_t* __restrict__ BtF, ushort_t* __restrict__ BtB, ushort_t* __restrict__ BtD) {
    const int mat = blockIdx.z;
    const float* U = (mat == 0) ? Uf : (mat == 1) ? Ub : Ud;
    ushort_t* Bt   = (mat == 0) ? BtF : (mat == 1) ? BtB : BtD;
    const int c  = blockIdx.y;          // chunk
    const int ct = blockIdx.x * 64;     // gcol tile
    const int kb = c * 32;

    __shared__ float tile[32][65];
    const int gc = threadIdx.x & 63;
    const int j0 = threadIdx.x >> 6;    // 0..3
#pragma unroll
    for (int s = 0; s < 8; ++s) {
        const int j = j0 * 8 + s;
        tile[j][gc] = U[(size_t)(kb + j) * GN + ct + gc];
    }
    __syncthreads();
    const int j  = threadIdx.x & 31;
    const int g0 = threadIdx.x >> 5;    // 0..7
#pragma unroll
    for (int p = 0; p < 8; ++p) {
        const int gcl = p * 8 + g0;
        Bt[((size_t)c * GN + ct + gcl) * 32 + j] = f2bf(tile[j][gcl]);
    }
}

// Logits B (3-term) via LDS tile transpose: Wot2[chunk 0..31][col][j]; 0..15 hi, 16..31 lo.
__global__ __launch_bounds__(256) void precomp_Wot2(
    const float* __restrict__ Wo, ushort_t* __restrict__ Wot) {
    const int c  = blockIdx.y;          // 0..31
    const int ct = blockIdx.x * 64;
    const int kb = (c < 16) ? c * 32 : (c - 16) * 32;

    __shared__ float tile[32][65];
    const int gc = threadIdx.x & 63;
    const int j0 = threadIdx.x >> 6;
#pragma unroll
    for (int s = 0; s < 8; ++s) {
        const int j = j0 * 8 + s;
        tile[j][gc] = Wo[(size_t)(kb + j) * VN + ct + gc];
    }
    __syncthreads();
    const int j  = threadIdx.x & 31;
    const int g0 = threadIdx.x >> 5;
#pragma unroll
    for (int p = 0; p < 8; ++p) {
        const int gcl = p * 8 + g0;
        float u = tile[j][gcl];
        ushort_t hi = f2bf(u);
        Wot[((size_t)c * VN + ct + gcl) * 32 + j] = (c >= 16) ? f2bf(u - bf2f(hi)) : hi;
    }
}

__global__ void dec_init(const ushort_t* __restrict__ hf, const ushort_t* __restrict__ hb,
                         ushort_t* __restrict__ hd) {
    int i = blockIdx.x * blockDim.x + threadIdx.x;
    if (i >= BN_ * HN) return;
    int row = i >> 9, col = i & (HN - 1);
    float h = bf2f(hf[(size_t)row * HC + col]) + bf2f(hf[(size_t)row * HC + HN + col])
            + bf2f(hb[(size_t)row * HC + col]) + bf2f(hb[(size_t)row * HC + HN + col]);
    ushort_t hi = f2bf(h);
    hd[(size_t)row * HC + col] = hi;
    hd[(size_t)row * HC + HN + col] = f2bf(h - bf2f(hi));
}

// ===== Encoder step: both dirs, MT=64, 4 waves of 64x16x3gates. Grid (128,8). =====
// XCD = bx%8, dir = bx&4, rtile = (bx>>3)*4 + (bx&3). 4 blocks/CU (LDS 32KB).
// 16 chunks; per chunk stage {A-hi 4K, B 12K}; 1 MFMA term (bf16 h). vmcnt(4).
// t==0 fast path: h_in == 0 -> skip staging/MFMA (acc=0, ho=0).
__global__ __launch_bounds__(256, 4) void enc_step(
    const ushort_t* __restrict__ hf_in, ushort_t* __restrict__ hf_out,
    const ushort_t* __restrict__ BtF, const float* __restrict__ brF, const float* __restrict__ Pf,
    const ushort_t* __restrict__ hb_in, ushort_t* __restrict__ hb_out,
    const ushort_t* __restrict__ BtB, const float* __restrict__ brB, const float* __restrict__ Pb,
    const int* __restrict__ src, int t) {
    const int bx = blockIdx.x;
    const ushort_t* hin; ushort_t* hout; const ushort_t* Bt; const float* brec; const float* P; int rev;
    if ((bx & 4) == 0) { hin = hf_in; hout = hf_out; Bt = BtF; brec = brF; P = Pf; rev = 0; }
    else               { hin = hb_in; hout = hb_out; Bt = BtB; brec = brB; P = Pb; rev = 1; }
    const int bm = ((bx >> 3) * 4 + (bx & 3)) * 64;
    const int bj = blockIdx.y * 64;
    const int tid = threadIdx.x;
    const int lane = tid & 63;
    const int w = tid >> 6;
    const int fl = lane & 15;
    const int fke = (((lane >> 4) ^ ((lane >> 1) & 3)) * 8);    // swizzled read slot
    const int lr = lane >> 2;
    const int lk = (((lane & 3) ^ ((lane >> 3) & 3)) * 8);      // swizzled global slot
    const int fq = lane >> 4;

    __shared__ __align__(16) short SM[2][256 * 32];   // A-hi 0..63, B 64..255

    f32x4 acc[3][4];
#pragma unroll
    for (int g = 0; g < 3; g++)
#pragma unroll
        for (int i = 0; i < 4; i++) acc[g][i] = (f32x4){0.f, 0.f, 0.f, 0.f};

    auto stage = [&](int buf, int kc) {
        const int ah = kc * 32;
        const int r0a = w * 16;
        gload16(hin + (size_t)(bm + r0a + lr) * HC + ah + lk, &SM[buf][r0a * 32]);
#pragma unroll
        for (int s = 0; s < 3; ++s) {
            const int r0 = w * 48 + s * 16;
            const int r = r0 + lr;
            const int gcol = ((r >> 6) << 9) + bj + (r & 63);
            gload16(Bt + ((size_t)kc * GN + gcol) * 32 + lk, &SM[buf][(64 + r0) * 32]);
        }
    };
    auto compute = [&](int cur) {
        const short* Ab = &SM[cur][0];
        const short* Bb = &SM[cur][64 * 32];
        bf16x8 ah[4];
#pragma unroll
        for (int i = 0; i < 4; i++)
            ah[i] = *(const bf16x8*)&Ab[(i * 16 + fl) * 32 + fke];
#pragma unroll
        for (int g = 0; g < 3; g++) {
            bf16x8 bfr = *(const bf16x8*)&Bb[(g * 64 + w * 16 + fl) * 32 + fke];
#pragma unroll
            for (int i = 0; i < 4; i++)
                acc[g][i] = __builtin_amdgcn_mfma_f32_16x16x32_bf16(ah[i], bfr, acc[g][i], 0, 0, 0);
        }
    };

    if (t > 0) {   // t==0: h_in == 0 -> GEMM result is 0; skip staging entirely
        stage(0, 0);
        for (int kc = 0; kc < 16; ++kc) {
            if (kc < 15) { stage((kc + 1) & 1, kc + 1); waitcnt_vm<4>(); }
            else         { waitcnt_vm<0>(); }
            barrier_();
            compute(kc & 1);
            barrier_();
        }
    }

#pragma unroll
    for (int i = 0; i < 4; i++) {
#pragma unroll
        for (int q = 0; q < 4; q++) {
            const int row = bm + i * 16 + fq * 4 + q;
            const int idx = src[row * SN + (rev ? (SN - 1 - t) : t)];
            const float* Pr = P + (size_t)idx * GN;
            const int col = bj + w * 16 + fl;
            float rz = acc[0][i][q] + brec[col];
            float rr = acc[1][i][q] + brec[HN + col];
            float rh = acc[2][i][q] + brec[2 * HN + col];
            float z = 1.f / (1.f + expf(-(Pr[col] + rz)));
            float r = 1.f / (1.f + expf(-(Pr[HN + col] + rr)));
            float hh = tanhf(Pr[2 * HN + col] + r * rh);
            float ho = (t > 0) ? (bf2f(hin[(size_t)row * HC + col]) + bf2f(hin[(size_t)row * HC + HN + col]))
                               : 0.f;
            float hnew = z * ho + (1.f - z) * hh;
            ushort_t hib = f2bf(hnew);
            hout[(size_t)row * HC + col] = hib;
            hout[(size_t)row * HC + HN + col] = f2bf(hnew - bf2f(hib));
        }
    }
}

// ===== Fused decoder step t (16 chunks, 1-term) + logits of t-1 (16 chunks, 3-term). =====
// dec buffer: A-hi 0..63, B 64..255 -> 16KB/buf.
// logits buffer: A-hi 0..63, A-lo 64..127, Wh 128..191, Wl 192..255 -> 16KB/buf.
// LDS 32KB, grid 768 = 3 blocks/CU.
__global__ __launch_bounds__(256, 3) void dec_fused(
    const ushort_t* __restrict__ hin, ushort_t* __restrict__ hout,
    const ushort_t* __restrict__ BtD, const float* __restrict__ brD, const float* __restrict__ Pd,
    const int* __restrict__ tgt, const ushort_t* __restrict__ Wot,
    const float* __restrict__ bo, float* __restrict__ out, int t) {
    const int bx = blockIdx.x;
    const int tid = threadIdx.x;
    const int lane = tid & 63;
    const int w = tid >> 6;
    const int fl = lane & 15;
    const int fke = (((lane >> 4) ^ ((lane >> 1) & 3)) * 8);
    const int lr = lane >> 2;
    const int lk = (((lane & 3) ^ ((lane >> 3) & 3)) * 8);
    const int fq = lane >> 4;

    __shared__ __align__(16) short SM[2][256 * 32];

    if (bx < 512) {
        const int bm = (bx & 63) * 64;
        const int bj = (bx >> 6) * 64;

        f32x4 acc[3][4];
#pragma unroll
        for (int g = 0; g < 3; g++)
#pragma unroll
            for (int i = 0; i < 4; i++) acc[g][i] = (f32x4){0.f, 0.f, 0.f, 0.f};

        auto stage = [&](int buf, int kc) {
            const int ah = kc * 32;
            const int r0a = w * 16;
            gload16(hin + (size_t)(bm + r0a + lr) * HC + ah + lk, &SM[buf][r0a * 32]);
#pragma unroll
            for (int s = 0; s < 3; ++s) {
                const int r0 = w * 48 + s * 16;
                const int r = r0 + lr;
                const int gcol = ((r >> 6) << 9) + bj + (r & 63);
                gload16(BtD + ((size_t)kc * GN + gcol) * 32 + lk, &SM[buf][(64 + r0) * 32]);
            }
        };
        auto compute = [&](int cur) {
            const short* Ab = &SM[cur][0];
            const short* Bb = &SM[cur][64 * 32];
            bf16x8 ah[4];
#pragma unroll
            for (int i = 0; i < 4; i++)
                ah[i] = *(const bf16x8*)&Ab[(i * 16 + fl) * 32 + fke];
#pragma unroll
            for (int g = 0; g < 3; g++) {
                bf16x8 bfr = *(const bf16x8*)&Bb[(g * 64 + w * 16 + fl) * 32 + fke];
#pragma unroll
                for (int i = 0; i < 4; i++)
                    acc[g][i] = __builtin_amdgcn_mfma_f32_16x16x32_bf16(ah[i], bfr, acc[g][i], 0, 0, 0);
            }
        };

        stage(0, 0);
        for (int kc = 0; kc < 16; ++kc) {
            if (kc < 15) { stage((kc + 1) & 1, kc + 1); waitcnt_vm<4>(); }
            else         { waitcnt_vm<0>(); }
            barrier_();
            compute(kc & 1);
            barrier_();
        }

#pragma unroll
        for (int i = 0; i < 4; i++) {
#pragma unroll
            for (int q = 0; q < 4; q++) {
                const int row = bm + i * 16 + fq * 4 + q;
                const int idx = (t == 0) ? BOW_ : tgt[row * TN + (t - 1)];
                const float* Pr = Pd + (size_t)idx * GN;
                const int col = bj + w * 16 + fl;
                float rz = acc[0][i][q] + brD[col];
                float rr = acc[1][i][q] + brD[HN + col];
                float rh = acc[2][i][q] + brD[2 * HN + col];
                float z = 1.f / (1.f + expf(-(Pr[col] + rz)));
                float r = 1.f / (1.f + expf(-(Pr[HN + col] + rr)));
                float hh = tanhf(Pr[2 * HN + col] + r * rh);
                float ho = bf2f(hin[(size_t)row * HC + col]) + bf2f(hin[(size_t)row * HC + HN + col]);
                float hnew = z * ho + (1.f - z) * hh;
                ushort_t hib = f2bf(hnew);
                hout[(size_t)row * HC + col] = hib;
                hout[(size_t)row * HC + HN + col] = f2bf(hnew - bf2f(hib));
            }
        }
    } else {
        if (t == 0) return;
        const int l = bx - 512;
        const int bm = (l & 63) * 64;
        const int bn = (l >> 6) * 64;

        f32x4 acc[4];
#pragma unroll
        for (int i = 0; i < 4; i++) acc[i] = (f32x4){0.f, 0.f, 0.f, 0.f};

        // 16 chunks; per chunk stage {Ahi, Alo, Wohi(kc), Wolo(16+kc)} once;
        // acc += Ahi x Wh + Alo x Wh + Ahi x Wl.
        auto stage = [&](int buf, int kc) {
            const int ah = kc * 32;
            const int al = 512 + kc * 32;
            const int r0 = w * 16;
            gload16(hin + (size_t)(bm + r0 + lr) * HC + ah + lk, &SM[buf][r0 * 32]);
            gload16(hin + (size_t)(bm + r0 + lr) * HC + al + lk, &SM[buf][(64 + r0) * 32]);
            gload16(Wot + ((size_t)kc * VN + bn + r0 + lr) * 32 + lk, &SM[buf][(128 + r0) * 32]);
            gload16(Wot + ((size_t)(16 + kc) * VN + bn + r0 + lr) * 32 + lk, &SM[buf][(192 + r0) * 32]);
        };
        auto compute = [&](int cur) {
            const short* Ab = &SM[cur][0];
            bf16x8 wh = *(const bf16x8*)&SM[cur][(128 + w * 16 + fl) * 32 + fke];
            bf16x8 wl = *(const bf16x8*)&SM[cur][(192 + w * 16 + fl) * 32 + fke];
#pragma unroll
            for (int i = 0; i < 4; i++) {
                bf16x8 ah = *(const bf16x8*)&Ab[(i * 16 + fl) * 32 + fke];
                bf16x8 al = *(const bf16x8*)&Ab[(64 + i * 16 + fl) * 32 + fke];
                acc[i] = __builtin_amdgcn_mfma_f32_16x16x32_bf16(ah, wh, acc[i], 0, 0, 0);
                acc[i] = __builtin_amdgcn_mfma_f32_16x16x32_bf16(al, wh, acc[i], 0, 0, 0);
                acc[i] = __builtin_amdgcn_mfma_f32_16x16x32_bf16(ah, wl, acc[i], 0, 0, 0);
            }
        };

        stage(0, 0);
        for (int kc = 0; kc < 16; ++kc) {
            if (kc < 15) { stage((kc + 1) & 1, kc + 1); waitcnt_vm<4>(); }
            else         { waitcnt_vm<0>(); }
            barrier_();
            compute(kc & 1);
            barrier_();
        }

#pragma unroll
        for (int i = 0; i < 4; i++) {
#pragma unroll
            for (int q = 0; q < 4; q++) {
                const int row = bm + i * 16 + fq * 4 + q;
                const int col = bn + w * 16 + fl;
                out[(size_t)row * (TN * VN) + (t - 1) * VN + col] = acc[i][q] + bo[col];
            }
        }
    }
}

// standalone logits for the final decoder output (t = TN-1), 16 chunks all-once
__global__ __launch_bounds__(256) void logits_mfma(
    const ushort_t* __restrict__ hin, const ushort_t* __restrict__ Wot,
    const float* __restrict__ bo, float* __restrict__ out, int t) {
    const int bm = blockIdx.x * 64;
    const int bn = blockIdx.y * 64;
    const int tid = threadIdx.x;
    const int lane = tid & 63;
    const int w = tid >> 6;

    __shared__ __align__(16) short SM[2][256 * 32];

    f32x4 acc[4];
#pragma unroll
    for (int i = 0; i < 4; i++) acc[i] = (f32x4){0.f, 0.f, 0.f, 0.f};

    const int fl = lane & 15;
    const int fke = (((lane >> 4) ^ ((lane >> 1) & 3)) * 8);
    const int lr = lane >> 2;
    const int lk = (((lane & 3) ^ ((lane >> 3) & 3)) * 8);

    auto stage = [&](int buf, int kc) {
        const int ah = kc * 32;
        const int al = 512 + kc * 32;
        const int r0 = w * 16;
        gload16(hin + (size_t)(bm + r0 + lr) * HC + ah + lk, &SM[buf][r0 * 32]);
        gload16(hin + (size_t)(bm + r0 + lr) * HC + al + lk, &SM[buf][(64 + r0) * 32]);
        gload16(Wot + ((size_t)kc * VN + bn + r0 + lr) * 32 + lk, &SM[buf][(128 + r0) * 32]);
        gload16(Wot + ((size_t)(16 + kc) * VN + bn + r0 + lr) * 32 + lk, &SM[buf][(192 + r0) * 32]);
    };
    auto compute = [&](int cur) {
        const short* Ab = &SM[cur][0];
        bf16x8 wh = *(const bf16x8*)&SM[cur][(128 + w * 16 + fl) * 32 + fke];
        bf16x8 wl = *(const bf16x8*)&SM[cur][(192 + w * 16 + fl) * 32 + fke];
#pragma unroll
        for (int i = 0; i < 4; i++) {
            bf16x8 ah = *(const bf16x8*)&Ab[(i * 16 + fl) * 32 + fke];
            bf16x8 al = *(const bf16x8*)&Ab[(64 + i * 16 + fl) * 32 + fke];
            acc[i] = __builtin_amdgcn_mfma_f32_16x16x32_bf16(ah, wh, acc[i], 0, 0, 0);
            acc[i] = __builtin_amdgcn_mfma_f32_16x16x32_bf16(al, wh, acc[i], 0, 0, 0);
            acc[i] = __builtin_amdgcn_mfma_f32_16x16x32_bf16(ah, wl, acc[i], 0, 0, 0);
        }
    };

    stage(0, 0);
    for (int kc = 0; kc < 16; ++kc) {
        if (kc < 15) { stage((kc + 1) & 1, kc + 1); waitcnt_vm<4>(); }
        else         { waitcnt_vm<0>(); }
        barrier_();
        compute(kc & 1);
        barrier_();
    }

    const int fq = lane >> 4;
#pragma unroll
    for (int i = 0; i < 4; i++) {
#pragma unroll
        for (int q = 0; q < 4; q++) {
            const int row = bm + i * 16 + fq * 4 + q;
            const int col = bn + w * 16 + fl;
            out[(size_t)row * (TN * VN) + t * VN + col] = acc[i][q] + bo[col];
        }
    }
}

extern "C" void kernel_launch(void* const* d_in, const int* in_sizes, int n_in,
                              void* d_out, int out_size, void* d_ws, size_t ws_size,
                              hipStream_t stream) {
    const int* source    = (const int*)d_in[0];
    const int* targets   = (const int*)d_in[1];
    const float* src_emb = (const float*)d_in[2];
    const float* tgt_emb = (const float*)d_in[3];
    const float* Wf = (const float*)d_in[4];
    const float* Uf = (const float*)d_in[5];
    const float* bf = (const float*)d_in[6];
    const float* Wb = (const float*)d_in[7];
    const float* Ub = (const float*)d_in[8];
    const float* bb = (const float*)d_in[9];
    const float* Wd = (const float*)d_in[10];
    const float* Ud = (const float*)d_in[11];
    const float* bd = (const float*)d_in[12];
    const float* Wo = (const float*)d_in[13];
    const float* bo = (const float*)d_in[14];
    float* out = (float*)d_out;

    char* ws = (char*)d_ws;
    ushort_t* BtF = (ushort_t*)(ws);                    // 16*1536*32*2 = 1572864 each
    ushort_t* BtB = (ushort_t*)(ws + 1572864);
    ushort_t* BtD = (ushort_t*)(ws + 2 * 1572864);
    ushort_t* Wot = (ushort_t*)(ws + 3 * 1572864);      // 32*256*32*2 = 524288
    float*    Pf  = (float*)   (ws + 3 * 1572864 + 524288);  // 3*256*1536*4 = 4718592
    float*    Pb  = Pf + VN * GN;
    float*    Pd  = Pb + VN * GN;
    char* hbase = ws + 3 * 1572864 + 524288 + 4718592;  // 4 x 4096*1024*2 = 4 x 8388608
    ushort_t* hf0 = (ushort_t*)(hbase);
    ushort_t* hf1 = (ushort_t*)(hbase + 8388608);
    ushort_t* hb0 = (ushort_t*)(hbase + 2 * 8388608);
    ushort_t* hb1 = (ushort_t*)(hbase + 3 * 8388608);

    precomp_P<<<dim3(4, 24, 3), 256, 0, stream>>>(src_emb, tgt_emb, Wf, bf, Wb, bb, Wd, bd, Pf, Pb, Pd);
    precomp_Bt2<<<dim3(24, 16, 3), 256, 0, stream>>>(Uf, Ub, Ud, BtF, BtB, BtD);
    precomp_Wot2<<<dim3(4, 32), 256, 0, stream>>>(Wo, Wot);

    // encoder: grid (128,8): XCD 0-3 fwd / 4-7 bwd, 64-row tiles, 4 blocks/CU.
    // t==0 reads no h state (fast path), so hf0/hb0 need no zero-init.
    for (int t = 0; t < SN; t++) {
        const ushort_t* hfi = (t & 1) ? hf1 : hf0; ushort_t* hfo = (t & 1) ? hf0 : hf1;
        const ushort_t* hbi = (t & 1) ? hb1 : hb0; ushort_t* hbo = (t & 1) ? hb0 : hb1;
        enc_step<<<dim3(128, 8), 256, 0, stream>>>(
            hfi, hfo, BtF, bf + GN, Pf,
            hbi, hbo, BtB, bb + GN, Pb,
            source, t);
    }
    dec_init<<<(BN_ * HN + 255) / 256, 256, 0, stream>>>(hf0, hb0, hb1);

    // fused decoder step t + logits(t-1); ping-pong hb1 <-> hf1
    for (int t = 0; t < TN; t++) {
        const ushort_t* hdi = (t & 1) ? hf1 : hb1; ushort_t* hdo = (t & 1) ? hb1 : hf1;
        dec_fused<<<768, 256, 0, stream>>>(
            hdi, hdo, BtD, bd + GN, Pd, targets, Wot, bo, out, t);
    }
    // final logits for t = 23 output (hdo of t=23 is hb1 since 23 is odd)
    logits_mfma<<<dim3(64, 4), 256, 0, stream>>>(hb1, Wot, bo, out, TN - 1);
}